// Round 12
// baseline (216.969 us; speedup 1.0000x reference)
//
#include <hip/hip_runtime.h>
#include <math.h>

// Problem constants (setup_inputs: bs=16, nq=550, nc=91, nt=48, group_num=11)
#define BS 16
#define NQ 550
#define NC 91
#define NT 48
#define GN 11
#define GQ 50                 // queries per group
#define NTOT (BS * NT)        // 768
#define NROW 48               // LSA rows (targets) after reference transpose
#define MCOL 50               // LSA cols (queries)
#define NPAIR (GN * NT)       // 528
#define NLSA (BS * GN)        // 176 LSA blocks

// ---------------- focal (class) cost: fast f32 (R4/R6-proven) ---------------
__device__ __forceinline__ float focal_cost_f32(float x) {
    float prob = 1.0f / (1.0f + __expf(-x));
    float q = 1.0f - prob;
    float lneg = __logf(q + 1e-8f);
    float lpos = __logf(prob + 1e-8f);
    float neg = 0.75f * (prob * prob) * (-lneg);
    float pos = 0.25f * (q * q) * (-lpos);
    return pos - neg;
}

// ---------------- one C element, f32 __f*_rn box math ------------------------
__device__ __forceinline__ float cost_element(
    const float* __restrict__ logits,
    const float* __restrict__ pboxes, const int* __restrict__ labels,
    const float* __restrict__ tboxes, int p, int t)
{
    const float* pb = pboxes + (long)p * 6;
    float pcx = pb[0], pcy = pb[1], pl = pb[2], pr = pb[3], ptt = pb[4], pbo = pb[5];
    const float* tb = tboxes + (long)t * 6;
    float tcx = tb[0], tcy = tb[1], tl = tb[2], tr = tb[3], ttt = tb[4], tbo = tb[5];

    float c3d = __fadd_rn(fabsf(__fsub_rn(pcx, tcx)), fabsf(__fsub_rn(pcy, tcy)));
    float cbb = __fadd_rn(
                  __fadd_rn(
                    __fadd_rn(fabsf(__fsub_rn(pl, tl)), fabsf(__fsub_rn(pr, tr))),
                    fabsf(__fsub_rn(ptt, ttt))),
                  fabsf(__fsub_rn(pbo, tbo)));

    float px1 = __fsub_rn(pcx, pl), py1 = __fsub_rn(pcy, ptt);
    float px2 = __fadd_rn(pcx, pr), py2 = __fadd_rn(pcy, pbo);
    float tx1 = __fsub_rn(tcx, tl), ty1 = __fsub_rn(tcy, ttt);
    float tx2 = __fadd_rn(tcx, tr), ty2 = __fadd_rn(tcy, tbo);

    float area1 = __fmul_rn(__fsub_rn(px2, px1), __fsub_rn(py2, py1));
    float area2 = __fmul_rn(__fsub_rn(tx2, tx1), __fsub_rn(ty2, ty1));
    float ltx = fmaxf(px1, tx1), lty = fmaxf(py1, ty1);
    float rbx = fminf(px2, tx2), rby = fminf(py2, ty2);
    float wx = fmaxf(__fsub_rn(rbx, ltx), 0.0f);
    float wy = fmaxf(__fsub_rn(rby, lty), 0.0f);
    float inter = __fmul_rn(wx, wy);
    float uni = __fsub_rn(__fadd_rn(area1, area2), inter);
    float iou = __fdiv_rn(inter, uni);
    float ex1 = fminf(px1, tx1), ey1 = fminf(py1, ty1);
    float ex2 = fmaxf(px2, tx2), ey2 = fmaxf(py2, ty2);
    float ew = fmaxf(__fsub_rn(ex2, ex1), 0.0f);
    float eh = fmaxf(__fsub_rn(ey2, ey1), 0.0f);
    float earea = __fmul_rn(ew, eh);
    float giou = __fsub_rn(iou, __fdiv_rn(__fsub_rn(earea, uni), earea));
    float cgiou = -giou;

    float cclass = focal_cost_f32(logits[(long)p * NC + labels[t]]);

    float out = __fmul_rn(5.0f, cbb);
    out = __fadd_rn(out, __fmul_rn(10.0f, c3d));
    out = __fadd_rn(out, __fmul_rn(2.0f, cclass));
    out = __fadd_rn(out, __fmul_rn(2.0f, cgiou));
    return out;
}

// ---------------- cross-lane helpers ----------------------------------------
__device__ __forceinline__ double readlane_f64(double x, int l) {
    long long b = __double_as_longlong(x);
    int lo = __builtin_amdgcn_readlane((int)(b & 0xffffffffLL), l);
    int hi = __builtin_amdgcn_readlane((int)(b >> 32), l);
    return __longlong_as_double(((long long)hi << 32) | (unsigned int)lo);
}

// order-preserving f32 -> u32 map: a < b (float, no NaN) <=> fkey(a) < fkey(b).
__device__ __forceinline__ unsigned fkey_u32(float f) {
    unsigned b = __float_as_uint(f);
    return b ^ (unsigned)(((int)b >> 31) | 0x80000000);
}

// one within-row-of-16 DPP u32-min stage
template <int CTRL>
__device__ __forceinline__ unsigned dpp_min_u32(unsigned x) {
    unsigned t = (unsigned)__builtin_amdgcn_update_dpp((int)x, (int)x, CTRL, 0xf, 0xf, false);
    return (x < t) ? x : t;
}

// uniform 8-way select: 7 v_cndmask, depth 3; conditions are scalar bits
__device__ __forceinline__ float sel8(float a0, float a1, float a2, float a3,
                                      float a4, float a5, float a6, float a7,
                                      int lid) {
    bool b0 = (lid & 1) != 0, b1 = (lid & 2) != 0, b2 = (lid & 4) != 0;
    float x0 = b0 ? a1 : a0;
    float x1 = b0 ? a3 : a2;
    float x2 = b0 ? a5 : a4;
    float x3 = b0 ? a7 : a6;
    float y0 = b1 ? x1 : x0;
    float y1 = b1 ? x3 : x2;
    return b2 ? y1 : y0;
}

// wave-uniform 48-way select from NAMED pinned registers: switch on the
// scalar group id (uniform s_cbranch) + in-group 7-cndmask tree.
#define SEL48(dst, srow)                                                      \
    {                                                                         \
        int su_ = __builtin_amdgcn_readfirstlane(srow);                       \
        int lid_ = su_ & 7;                                                   \
        float g_;                                                             \
        switch (su_ >> 3) {                                                   \
          case 0:  g_ = sel8(t0,t1,t2,t3,t4,t5,t6,t7, lid_); break;           \
          case 1:  g_ = sel8(t8,t9,t10,t11,t12,t13,t14,t15, lid_); break;     \
          case 2:  g_ = sel8(t16,t17,t18,t19,t20,t21,t22,t23, lid_); break;   \
          case 3:  g_ = sel8(t24,t25,t26,t27,t28,t29,t30,t31, lid_); break;   \
          case 4:  g_ = sel8(t32,t33,t34,t35,t36,t37,t38,t39, lid_); break;   \
          default: g_ = sel8(t40,t41,t42,t43,t44,t45,t46,t47, lid_); break;   \
        }                                                                     \
        (dst) = g_;                                                           \
    }

// ---------------- mega kernel: blocks [0,176) = LSA, rest = cost matrix -----
// R12 = R11's register-table select with the DIAGNOSED spill mechanism fixed.
// R7/R11 both showed VGPR=36: the compiler SLP-merged the 48 identical
// one-time LDS loads into an indexable aggregate -> scratch (rule #20), so
// the "named scalars" never reached registers. Fix (rule #17): an opaque
// asm pin `asm("" : "+v"(tK))` on EACH loaded value breaks the merge and
// forces 48 distinct VGPR values; __launch_bounds__(256,1) lifts any
// occupancy-driven VGPR cap. Loop body identical to R8/R11 (both passed):
// u32-key DPP/SALU argmin, exact f64 duals, trajectory bit-identical to R8.
// Verdict counter: VGPR ~100 = pinned; VGPR ~36 = family dead, revert R8.
__global__ __launch_bounds__(256, 1) void mega_kernel(
    const float* __restrict__ logits,
    const float* __restrict__ pboxes,
    const int*   __restrict__ labels,
    const float* __restrict__ tboxes,
    float*       __restrict__ C,
    float*       __restrict__ pi,
    float*       __restrict__ ti)
{
    if (blockIdx.x >= NLSA) {
        long idx = (long)(blockIdx.x - NLSA) * 256 + threadIdx.x;
        if (idx >= (long)BS * NQ * NTOT) return;
        int t = (int)(idx % NTOT);
        int p = (int)(idx / NTOT);
        C[idx] = cost_element(logits, pboxes, labels, tboxes, p, t);
        return;
    }

    // ---- LSA block ----
    const int blk = blockIdx.x;          // 0..175
    const int b = blk / GN, g = blk % GN;
    const int tid = threadIdx.x;

    __shared__ float lcost[NROW * MCOL];   // [row i][col j], f32 staging

    // All 256 threads fill the 48x50 tile, then waves 1-3 exit.
    for (int k = tid; k < NROW * MCOL; k += 256) {
        int i = k % NROW, j = k / NROW;
        float cf = cost_element(logits, pboxes, labels, tboxes,
                                b * NQ + g * GQ + j, b * NT + i);
        lcost[i * MCOL + j] = cf;
    }
    __syncthreads();
    if (tid >= 64) return;

    const int lane = tid;
    const bool incol = (lane >= 1 && lane <= MCOL);
    const int cidx = incol ? lane - 1 : 0;
    const double INF = __builtin_inf();
    const float INFF = __builtin_inff();

    // ---- per-lane cost column in 48 NAMED, PINNED registers ----------------
    // The asm pin makes each value an opaque VGPR def: SLP/re-roll cannot
    // merge them into an indexable aggregate (the R7/R11 scratch cause).
#define LOADT(K) float t##K = lcost[(K) * MCOL + cidx]; asm("" : "+v"(t##K));
    LOADT(0)  LOADT(1)  LOADT(2)  LOADT(3)  LOADT(4)  LOADT(5)  LOADT(6)  LOADT(7)
    LOADT(8)  LOADT(9)  LOADT(10) LOADT(11) LOADT(12) LOADT(13) LOADT(14) LOADT(15)
    LOADT(16) LOADT(17) LOADT(18) LOADT(19) LOADT(20) LOADT(21) LOADT(22) LOADT(23)
    LOADT(24) LOADT(25) LOADT(26) LOADT(27) LOADT(28) LOADT(29) LOADT(30) LOADT(31)
    LOADT(32) LOADT(33) LOADT(34) LOADT(35) LOADT(36) LOADT(37) LOADT(38) LOADT(39)
    LOADT(40) LOADT(41) LOADT(42) LOADT(43) LOADT(44) LOADT(45) LOADT(46) LOADT(47)
#undef LOADT

    int    pcol_l = 0;    // p[lane]   (0 = unassigned)
    double urow_l = 0.0;  // u[p[lane]]
    double v_l    = 0.0;  // v[lane]
    int    way_l  = 0;
    double minv_l = INF;
    float  kprev  = INFF; // f32 image of minv_l (monotone)
    bool   used_l = false;

    for (int i = 1; i <= NROW; ++i) {
        if (lane == 0) { pcol_l = i; urow_l = 0.0; }  // p[0]=i, u[i]=0
        minv_l = INF;
        kprev  = INFF;
        used_l = false;
        int j0 = 0;
        double u_i0 = 0.0;     // u[i0]
        float cd32;
        SEL48(cd32, i - 1);    // row (i-1) from registers
        double cd = (double)cd32;

        for (int guard = 0; guard <= MCOL + 1; ++guard) {
            used_l = used_l || (lane == j0);
            bool freel = incol && !used_l;

            double cur = (cd - u_i0) - v_l;           // (cost - u) - v, ref order
            bool upd   = freel && (cur < minv_l);
            minv_l = upd ? cur : minv_l;
            way_l  = upd ? j0  : way_l;

            // f32 key: exact image of updated minv for free lanes, +inf else
            float kf = freel ? fminf(__double2float_rn(cur), kprev) : INFF;

            // argmin via u32 key: 4 within-row DPP stages -> row minima at
            // lanes 15/31/47/63 -> readlane x4 -> SALU min tree -> ballot.
            unsigned ukey = fkey_u32(kf);
            unsigned red = ukey;
            red = dpp_min_u32<0x111>(red);  // row_shr:1
            red = dpp_min_u32<0x112>(red);  // row_shr:2
            red = dpp_min_u32<0x114>(red);  // row_shr:4
            red = dpp_min_u32<0x118>(red);  // row_shr:8
            unsigned m0 = (unsigned)__builtin_amdgcn_readlane((int)red, 15);
            unsigned m1 = (unsigned)__builtin_amdgcn_readlane((int)red, 31);
            unsigned m2 = (unsigned)__builtin_amdgcn_readlane((int)red, 47);
            unsigned m3 = (unsigned)__builtin_amdgcn_readlane((int)red, 63);
            unsigned ka = (m0 < m1) ? m0 : m1;
            unsigned kb = (m2 < m3) ? m2 : m3;
            unsigned kmin = (ka < kb) ? ka : kb;

            unsigned long long mm = __ballot(ukey == kmin);
            int j1 = (int)__builtin_ctzll(mm);        // lowest lane = np.argmin

            int i0n = __builtin_amdgcn_readlane(pcol_l, j1);

            // next-row cost from pinned registers (uniform select, clamped;
            // value unused when i0n==0 and we break)
            int s = (i0n > 0) ? (i0n - 1) : 0;
            float cdn32;
            SEL48(cdn32, s);
            double cd_next = (double)cdn32;

            double delta = readlane_f64(minv_l, j1);  // exact f64 min value
            double u_nx  = readlane_f64(urow_l, j1);

            urow_l = used_l ? urow_l + delta : urow_l;
            v_l    = used_l ? v_l - delta    : v_l;
            minv_l = freel  ? minv_l - delta : minv_l;
            kprev  = __double2float_rn(minv_l);

            j0 = j1;
            if (i0n == 0) break;
            u_i0 = u_nx;
            cd   = cd_next;
        }

        // augment back-walk: p[j]=p[way[j]], moving urow with pcol
        int j = j0;
        while (j != 0) {
            int wj    = __builtin_amdgcn_readlane(way_l, j);
            int pr    = __builtin_amdgcn_readlane(pcol_l, wj);
            double ur = readlane_f64(urow_l, wj);
            if (lane == j) { pcol_l = pr; urow_l = ur; }
            j = wj;
        }
    }

    // Extraction: ascending query (column) order == reference order.
    unsigned long long asg = __ballot(incol && pcol_l != 0);
    if (incol && pcol_l != 0) {
        int k = __popcll(asg & ((1ull << lane) - 1));
        float* pib = pi + ((long)b * NPAIR + (long)g * NT);
        float* tib = ti + ((long)b * NPAIR + (long)g * NT);
        pib[k] = (float)(g * GQ + cidx);
        tib[k] = (float)(pcol_l - 1);
    }
}

extern "C" void kernel_launch(void* const* d_in, const int* in_sizes, int n_in,
                              void* d_out, int out_size, void* d_ws, size_t ws_size,
                              hipStream_t stream) {
    const float* logits = (const float*)d_in[0];   // [16,550,91] f32
    const float* pboxes = (const float*)d_in[1];   // [16,550,6] f32
    const int*   labels = (const int*)d_in[2];     // [16,48] i32
    const float* tboxes = (const float*)d_in[3];   // [16,48,6] f32

    float* out = (float*)d_out;
    float* C  = out;                               // 16*550*768
    float* pi = out + (long)BS * NQ * NTOT;
    float* ti = pi + (long)BS * NPAIR;

    long total = (long)BS * NQ * NTOT;
    int cost_blocks = (int)((total + 255) / 256);
    int mega_blocks = NLSA + cost_blocks;

    mega_kernel<<<mega_blocks, 256, 0, stream>>>(
        logits, pboxes, labels, tboxes, C, pi, ti);
}

// Round 13
// 161.126 us; speedup vs baseline: 1.3466x; 1.3466x over previous
//
#include <hip/hip_runtime.h>
#include <math.h>

// Problem constants (setup_inputs: bs=16, nq=550, nc=91, nt=48, group_num=11)
#define BS 16
#define NQ 550
#define NC 91
#define NT 48
#define GN 11
#define GQ 50                 // queries per group
#define NTOT (BS * NT)        // 768
#define NROW 48               // LSA rows (targets) after reference transpose
#define MCOL 50               // LSA cols (queries)
#define NPAIR (GN * NT)       // 528
#define NLSA (BS * GN)        // 176 LSA blocks
#define ROWBYTES (MCOL * 8)   // byte stride of one lcost row (f64)

// ---------------- focal (class) cost: fast f32 (R4/R6-proven) ---------------
__device__ __forceinline__ float focal_cost_f32(float x) {
    float prob = 1.0f / (1.0f + __expf(-x));
    float q = 1.0f - prob;
    float lneg = __logf(q + 1e-8f);
    float lpos = __logf(prob + 1e-8f);
    float neg = 0.75f * (prob * prob) * (-lneg);
    float pos = 0.25f * (q * q) * (-lpos);
    return pos - neg;
}

// ---------------- one C element, f32 __f*_rn box math ------------------------
__device__ __forceinline__ float cost_element(
    const float* __restrict__ logits,
    const float* __restrict__ pboxes, const int* __restrict__ labels,
    const float* __restrict__ tboxes, int p, int t)
{
    const float* pb = pboxes + (long)p * 6;
    float pcx = pb[0], pcy = pb[1], pl = pb[2], pr = pb[3], ptt = pb[4], pbo = pb[5];
    const float* tb = tboxes + (long)t * 6;
    float tcx = tb[0], tcy = tb[1], tl = tb[2], tr = tb[3], ttt = tb[4], tbo = tb[5];

    float c3d = __fadd_rn(fabsf(__fsub_rn(pcx, tcx)), fabsf(__fsub_rn(pcy, tcy)));
    float cbb = __fadd_rn(
                  __fadd_rn(
                    __fadd_rn(fabsf(__fsub_rn(pl, tl)), fabsf(__fsub_rn(pr, tr))),
                    fabsf(__fsub_rn(ptt, ttt))),
                  fabsf(__fsub_rn(pbo, tbo)));

    float px1 = __fsub_rn(pcx, pl), py1 = __fsub_rn(pcy, ptt);
    float px2 = __fadd_rn(pcx, pr), py2 = __fadd_rn(pcy, pbo);
    float tx1 = __fsub_rn(tcx, tl), ty1 = __fsub_rn(tcy, ttt);
    float tx2 = __fadd_rn(tcx, tr), ty2 = __fadd_rn(tcy, tbo);

    float area1 = __fmul_rn(__fsub_rn(px2, px1), __fsub_rn(py2, py1));
    float area2 = __fmul_rn(__fsub_rn(tx2, tx1), __fsub_rn(ty2, ty1));
    float ltx = fmaxf(px1, tx1), lty = fmaxf(py1, ty1);
    float rbx = fminf(px2, tx2), rby = fminf(py2, ty2);
    float wx = fmaxf(__fsub_rn(rbx, ltx), 0.0f);
    float wy = fmaxf(__fsub_rn(rby, lty), 0.0f);
    float inter = __fmul_rn(wx, wy);
    float uni = __fsub_rn(__fadd_rn(area1, area2), inter);
    float iou = __fdiv_rn(inter, uni);
    float ex1 = fminf(px1, tx1), ey1 = fminf(py1, ty1);
    float ex2 = fmaxf(px2, tx2), ey2 = fmaxf(py2, ty2);
    float ew = fmaxf(__fsub_rn(ex2, ex1), 0.0f);
    float eh = fmaxf(__fsub_rn(ey2, ey1), 0.0f);
    float earea = __fmul_rn(ew, eh);
    float giou = __fsub_rn(iou, __fdiv_rn(__fsub_rn(earea, uni), earea));
    float cgiou = -giou;

    float cclass = focal_cost_f32(logits[(long)p * NC + labels[t]]);

    float out = __fmul_rn(5.0f, cbb);
    out = __fadd_rn(out, __fmul_rn(10.0f, c3d));
    out = __fadd_rn(out, __fmul_rn(2.0f, cclass));
    out = __fadd_rn(out, __fmul_rn(2.0f, cgiou));
    return out;
}

// ---------------- cross-lane helpers ----------------------------------------
__device__ __forceinline__ double readlane_f64(double x, int l) {
    long long b = __double_as_longlong(x);
    int lo = __builtin_amdgcn_readlane((int)(b & 0xffffffffLL), l);
    int hi = __builtin_amdgcn_readlane((int)(b >> 32), l);
    return __longlong_as_double(((long long)hi << 32) | (unsigned int)lo);
}

// order-preserving f32 -> u32 map: a < b (float, no NaN) <=> fkey(a) < fkey(b).
// Bijective; -0 never arises here (f64 a-b with a==b rounds to +0), so u32
// equality == float equality on all reachable keys.
__device__ __forceinline__ unsigned fkey_u32(float f) {
    unsigned b = __float_as_uint(f);
    return b ^ (unsigned)(((int)b >> 31) | 0x80000000);
}

// one within-row-of-16 DPP u32-min stage
template <int CTRL>
__device__ __forceinline__ unsigned dpp_min_u32(unsigned x) {
    unsigned t = (unsigned)__builtin_amdgcn_update_dpp((int)x, (int)x, CTRL, 0xf, 0xf, false);
    return (x < t) ? x : t;
}

// ---------------- mega kernel: blocks [0,176) = LSA, rest = cost matrix -----
// R13 = R8 (verified 100.6 us) with two trajectory-identical chain shaves:
//  (1) per-lane rowbyte_l = (pcol-1)*ROWBYTES maintained OUTSIDE the inner
//      loop (phase start + back-walk); the inner-loop address becomes
//      readlane(rowbyte, j1) + per-lane base -> drops the dependent
//      multiply between readlane and ds_read (~6-8 cy).
//  (2) running argmin key kept in u32 domain (uprev updated in the load
//      shadow): per-iter path is cvt -> fkey -> umin; fkey(kprev) moved
//      off the critical path (~3-4 cy). fkey is monotone-bijective and -0
//      unreachable -> winner set bit-identical to R8.
// (R7/R11/R12 closed the register-table family: allocator spills regardless
// of named scalars + asm pins; VGPR=36 signature all three times.)
__global__ __launch_bounds__(256) void mega_kernel(
    const float* __restrict__ logits,
    const float* __restrict__ pboxes,
    const int*   __restrict__ labels,
    const float* __restrict__ tboxes,
    float*       __restrict__ C,
    float*       __restrict__ pi,
    float*       __restrict__ ti)
{
    if (blockIdx.x >= NLSA) {
        long idx = (long)(blockIdx.x - NLSA) * 256 + threadIdx.x;
        if (idx >= (long)BS * NQ * NTOT) return;
        int t = (int)(idx % NTOT);
        int p = (int)(idx / NTOT);
        C[idx] = cost_element(logits, pboxes, labels, tboxes, p, t);
        return;
    }

    // ---- LSA block ----
    const int blk = blockIdx.x;          // 0..175
    const int b = blk / GN, g = blk % GN;
    const int tid = threadIdx.x;

    __shared__ double lcost[NROW * MCOL];   // [row i][col j]

    // All 256 threads fill the 48x50 tile, then waves 1-3 exit.
    for (int k = tid; k < NROW * MCOL; k += 256) {
        int i = k % NROW, j = k / NROW;
        float cf = cost_element(logits, pboxes, labels, tboxes,
                                b * NQ + g * GQ + j, b * NT + i);
        lcost[i * MCOL + j] = (double)cf;
    }
    __syncthreads();
    if (tid >= 64) return;

    const int lane = tid;
    const bool incol = (lane >= 1 && lane <= MCOL);
    const int cidx = incol ? lane - 1 : 0;
    const double INF = __builtin_inf();
    // per-lane column base (byte address of lcost[0][cidx])
    const char* colbase = (const char*)lcost + ((long)cidx << 3);

    int    pcol_l   = 0;    // p[lane]   (0 = unassigned)
    int    rowbyte_l = 0;   // (p[lane]-1)*ROWBYTES, clamped >= 0
    double urow_l   = 0.0;  // u[p[lane]]
    double v_l      = 0.0;  // v[lane]
    int    way_l    = 0;
    double minv_l   = INF;
    unsigned uprev  = 0xFF800000u; // fkey(+inf) = u32 image of kprev
    bool   used_l   = false;

    for (int i = 1; i <= NROW; ++i) {
        if (lane == 0) {
            pcol_l = i; urow_l = 0.0;                  // p[0]=i, u[i]=0
            rowbyte_l = (i - 1) * ROWBYTES;
        }
        minv_l = INF;
        uprev  = 0xFF800000u;                          // fkey(+inf)
        used_l = false;
        int j0 = 0;
        double u_i0 = 0.0;     // u[i0]
        double cd = *(const double*)(colbase + (i - 1) * ROWBYTES);

        for (int guard = 0; guard <= MCOL + 1; ++guard) {
            used_l = used_l || (lane == j0);
            bool freel = incol && !used_l;

            double cur = (cd - u_i0) - v_l;           // (cost - u) - v, ref order
            bool upd   = freel && (cur < minv_l);
            minv_l = upd ? cur : minv_l;
            way_l  = upd ? j0  : way_l;

            // u32 key: umin(fkey(cvt(cur)), uprev) == fkey(fminf(cvt(cur),kprev))
            // by monotone bijectivity -> bit-identical winner set to R8.
            unsigned ucur = fkey_u32(__double2float_rn(cur));
            unsigned ukey = freel ? ((ucur < uprev) ? ucur : uprev)
                                  : 0xFFFFFFFFu;      // unreachable by free lanes

            // argmin: 4 within-row DPP stages -> row minima at lanes
            // 15/31/47/63 -> readlane x4 -> SALU min tree -> ballot.
            unsigned red = ukey;
            red = dpp_min_u32<0x111>(red);  // row_shr:1
            red = dpp_min_u32<0x112>(red);  // row_shr:2
            red = dpp_min_u32<0x114>(red);  // row_shr:4
            red = dpp_min_u32<0x118>(red);  // row_shr:8
            unsigned m0 = (unsigned)__builtin_amdgcn_readlane((int)red, 15);
            unsigned m1 = (unsigned)__builtin_amdgcn_readlane((int)red, 31);
            unsigned m2 = (unsigned)__builtin_amdgcn_readlane((int)red, 47);
            unsigned m3 = (unsigned)__builtin_amdgcn_readlane((int)red, 63);
            unsigned ka = (m0 < m1) ? m0 : m1;
            unsigned kb = (m2 < m3) ? m2 : m3;
            unsigned kmin = (ka < kb) ? ka : kb;

            unsigned long long mm = __ballot(ukey == kmin);
            int j1 = (int)__builtin_ctzll(mm);        // lowest lane = np.argmin

            // two independent readlanes issue back-to-back:
            int offb = __builtin_amdgcn_readlane(rowbyte_l, j1); // byte offset
            int i0n  = __builtin_amdgcn_readlane(pcol_l, j1);    // break test

            // next-row load: base + SGPR offset (no multiply on the path).
            // offb is 0 for unassigned winner (pcol==0) -> safe row-0 read,
            // value unused when we break (R8 clamp semantics).
            double cd_next = *(const double*)(colbase + offb);

            double delta = readlane_f64(minv_l, j1);  // exact f64 min value
            double u_nx  = readlane_f64(urow_l, j1);

            // f64 dual updates + key image update, in the load shadow
            urow_l = used_l ? urow_l + delta : urow_l;
            v_l    = used_l ? v_l - delta    : v_l;
            minv_l = freel  ? minv_l - delta : minv_l;
            uprev  = fkey_u32(__double2float_rn(minv_l));

            j0 = j1;
            if (i0n == 0) break;
            u_i0 = u_nx;
            cd   = cd_next;
        }

        // augment back-walk: p[j]=p[way[j]], moving urow (and rowbyte) along
        int j = j0;
        while (j != 0) {
            int wj    = __builtin_amdgcn_readlane(way_l, j);
            int pr    = __builtin_amdgcn_readlane(pcol_l, wj);
            double ur = readlane_f64(urow_l, wj);
            if (lane == j) {
                pcol_l = pr; urow_l = ur;
                rowbyte_l = (pr - 1) * ROWBYTES;       // pr >= 1 on the walk
            }
            j = wj;
        }
    }

    // Extraction: ascending query (column) order == reference order.
    unsigned long long asg = __ballot(incol && pcol_l != 0);
    if (incol && pcol_l != 0) {
        int k = __popcll(asg & ((1ull << lane) - 1));
        float* pib = pi + ((long)b * NPAIR + (long)g * NT);
        float* tib = ti + ((long)b * NPAIR + (long)g * NT);
        pib[k] = (float)(g * GQ + cidx);
        tib[k] = (float)(pcol_l - 1);
    }
}

extern "C" void kernel_launch(void* const* d_in, const int* in_sizes, int n_in,
                              void* d_out, int out_size, void* d_ws, size_t ws_size,
                              hipStream_t stream) {
    const float* logits = (const float*)d_in[0];   // [16,550,91] f32
    const float* pboxes = (const float*)d_in[1];   // [16,550,6] f32
    const int*   labels = (const int*)d_in[2];     // [16,48] i32
    const float* tboxes = (const float*)d_in[3];   // [16,48,6] f32

    float* out = (float*)d_out;
    float* C  = out;                               // 16*550*768
    float* pi = out + (long)BS * NQ * NTOT;
    float* ti = pi + (long)BS * NPAIR;

    long total = (long)BS * NQ * NTOT;
    int cost_blocks = (int)((total + 255) / 256);
    int mega_blocks = NLSA + cost_blocks;

    mega_kernel<<<mega_blocks, 256, 0, stream>>>(
        logits, pboxes, labels, tboxes, C, pi, ti);
}